// Round 11
// baseline (136.294 us; speedup 1.0000x reference)
//
#include <hip/hip_runtime.h>
#include <math.h>

#define NPOS  16384
#define LBAG  30
#define NFEAT 40960
#define HDIM  512          // per side
#define MT    16           // positions per block (mlp2)

typedef short bf16x8 __attribute__((ext_vector_type(8)));
typedef float f32x4  __attribute__((ext_vector_type(4)));
typedef const __attribute__((address_space(1))) void gv_t;   // global ptr for DMA
typedef __attribute__((address_space(3))) void lv_t;         // LDS ptr for DMA

__device__ __forceinline__ unsigned int f2bf(float f) {
    unsigned int u = __float_as_uint(f);
    return (u + 0x7fffu + ((u >> 16) & 1u)) >> 16;
}
__device__ __forceinline__ float clip01(float v) { return fminf(fmaxf(v, 0.f), 1.f); }

// ---------------------------------------------------------------------------
// Prep 1: emb fp32 -> bf16 single table [NFEAT][512] (uint pairs).
// ---------------------------------------------------------------------------
__global__ __launch_bounds__(256) void cvt_emb(const float* __restrict__ src,
                                               unsigned int* __restrict__ dst) {
    const int nchunk = NFEAT * HDIM / 8;
    int c = blockIdx.x * 256 + threadIdx.x;
    const int stride = gridDim.x * 256;
    for (; c < nchunk; c += stride) {
        float4 f0 = ((const float4*)src)[(size_t)c * 2];
        float4 f1 = ((const float4*)src)[(size_t)c * 2 + 1];
        uint4 o;
        o.x = f2bf(f0.x) | (f2bf(f0.y) << 16);
        o.y = f2bf(f0.z) | (f2bf(f0.w) << 16);
        o.z = f2bf(f1.x) | (f2bf(f1.y) << 16);
        o.w = f2bf(f1.z) | (f2bf(f1.w) << 16);
        ((uint4*)dst)[c] = o;
    }
}

// ---------------------------------------------------------------------------
// Prep 2: W1 [128][1024] fp32 -> bf16 in MFMA B-fragment order.
//   B[k][j] = W1[j][k], j = nf*16 + (lane&15), k = ks*32 + (lane>>4)*8 + b
// ---------------------------------------------------------------------------
__global__ __launch_bounds__(256) void prep_w1(const float* __restrict__ W1,
                                               unsigned int* __restrict__ dst) {
    int c = blockIdx.x * 256 + threadIdx.x;
    if (c >= 8 * 32 * 64) return;
    int l  = c & 63;
    int ks = (c >> 6) & 31;
    int nf = c >> 11;
    int o  = nf * 16 + (l & 15);
    int kb = ks * 32 + (l >> 4) * 8;
    float4 f0 = *(const float4*)(W1 + (size_t)o * 1024 + kb);
    float4 f1 = *(const float4*)(W1 + (size_t)o * 1024 + kb + 4);
    uint4 v;
    v.x = f2bf(f0.x) | (f2bf(f0.y) << 16);
    v.y = f2bf(f0.z) | (f2bf(f0.w) << 16);
    v.z = f2bf(f1.x) | (f2bf(f1.y) << 16);
    v.w = f2bf(f1.z) | (f2bf(f1.w) << 16);
    ((uint4*)dst)[c] = v;
}

// ---------------------------------------------------------------------------
// Kernel 1, round 11: XCD-sliced gather with ASYNC global_load_lds pipeline.
// r10 evidence: slicing fixed fabric traffic (FETCH 412->142 MB) but dur held
// at 78us with VGPR=16 -> ~1 gather in flight per wave, latency-serialized
// (r7/r8 showed the allocator refuses load buffering into VGPRs).
// global_load_lds needs NO destination VGPRs: in-flight depth is set by
// counted vmcnt, not the allocator. Ring of 8 x 1KB LDS slots per wave,
// PIPE=6 in flight; one DMA per row gathers 8 bags x 128B (per-lane global
// addr; LDS dest = wave-uniform slot base + lane*16). Slot-reuse distance
// 8 > 6 => consume ds_read is 2 iters old before its slot is re-written.
// Indices u16-packed (NFEAT<65536): each lane holds its bag's 30 ids in 15
// regs, extraction fully static. LDS 40960 B -> 4 blocks/CU, 16 waves/CU.
// ---------------------------------------------------------------------------
#define RING 8
#define PIPE 6

__global__ __launch_bounds__(256) void gather_slices(
    const int* __restrict__ stm_idx, const int* __restrict__ nstm_idx,
    const unsigned int* __restrict__ embbf,     // [NFEAT][256] uints (512 bf16)
    unsigned int* __restrict__ xg)              // [NPOS][512] uints, swizzled
{
    __shared__ __align__(16) char smem[40960];
    char*           ring  = smem;               // 4 waves x RING x 1KB
    unsigned short* sidx  = (unsigned short*)(smem + 32768);  // [128 bags][32]

    const int t     = threadIdx.x;
    const int slice = blockIdx.x & 7;
    const int pblk  = (blockIdx.x >> 3) * 64;

    // stage indices as u16, bag-major: sidx[bag*32 + r], bag = p*2+side
#pragma unroll
    for (int i = 0; i < 15; ++i) {
        int e = t + i * 256;                    // 0..3839
        if (e < 1920) {
            int p = e / 30, r = e - p * 30;
            sidx[(p * 2) * 32 + r] = (unsigned short)stm_idx[(pblk + p) * 30 + r];
        } else {
            int e2 = e - 1920;
            int p = e2 / 30, r = e2 - p * 30;
            sidx[(p * 2 + 1) * 32 + r] = (unsigned short)nstm_idx[(pblk + p) * 30 + r];
        }
    }
    __syncthreads();

    const int lane = t & 63, w = t >> 6;
    const int g  = lane >> 3;                   // lane-group 0..7 (one bag)
    const int li = lane & 7;                    // 16B chunk within 128B line
    char* ringw = ring + w * (RING * 1024);     // wave-private ring
    const char* gtab = (const char*)embbf;
    const size_t goff = (size_t)(slice * 128 + li * 16);   // per-lane global ofs

#pragma unroll 1
    for (int it = 0; it < 4; ++it) {
        const int bag  = it * 32 + w * 8 + g;   // 0..127
        const int p    = bag >> 1;
        const int side = bag & 1;

        // my bag's 30 ids -> 16 packed words (static indexing -> registers)
        const uint4* sb = (const uint4*)(sidx + bag * 32);
        const uint4 i0 = sb[0], i1 = sb[1], i2 = sb[2], i3 = sb[3];
        const unsigned int idw[16] = {i0.x, i0.y, i0.z, i0.w, i1.x, i1.y, i1.z, i1.w,
                                      i2.x, i2.y, i2.z, i2.w, i3.x, i3.y, i3.z, i3.w};

        float ac[8];
#pragma unroll
        for (int j = 0; j < 8; ++j) ac[j] = 0.f;

#define GLD(rr) do {                                                          \
            const unsigned int wd_  = idw[(rr) >> 1];                         \
            const unsigned int id_  = ((rr) & 1) ? (wd_ >> 16) : (wd_ & 0xffffu); \
            __builtin_amdgcn_global_load_lds(                                 \
                (gv_t*)(gtab + ((size_t)id_ << 10) + goff),                   \
                (lv_t*)(ringw + (((rr) & (RING - 1)) << 10)), 16, 0, 0);      \
        } while (0)

#define STEP(rr, KK) do {                                                     \
            asm volatile("s_waitcnt vmcnt(" #KK ")" ::: "memory");            \
            __builtin_amdgcn_sched_barrier(0);                                \
            const uint4 v = *(const uint4*)(ringw +                           \
                                (((rr) & (RING - 1)) << 10) + (lane << 4));   \
            ac[0] += __uint_as_float(v.x << 16);                              \
            ac[1] += __uint_as_float(v.x & 0xffff0000u);                      \
            ac[2] += __uint_as_float(v.y << 16);                              \
            ac[3] += __uint_as_float(v.y & 0xffff0000u);                      \
            ac[4] += __uint_as_float(v.z << 16);                              \
            ac[5] += __uint_as_float(v.z & 0xffff0000u);                      \
            ac[6] += __uint_as_float(v.w << 16);                              \
            ac[7] += __uint_as_float(v.w & 0xffff0000u);                      \
            if ((rr) + PIPE < LBAG) GLD((rr) + PIPE);                         \
        } while (0)

        // prologue: fill the pipe
        GLD(0); GLD(1); GLD(2); GLD(3); GLD(4); GLD(5);
        // steady state + drain (K = min(PIPE-1, 29-r))
        STEP( 0, 5); STEP( 1, 5); STEP( 2, 5); STEP( 3, 5); STEP( 4, 5);
        STEP( 5, 5); STEP( 6, 5); STEP( 7, 5); STEP( 8, 5); STEP( 9, 5);
        STEP(10, 5); STEP(11, 5); STEP(12, 5); STEP(13, 5); STEP(14, 5);
        STEP(15, 5); STEP(16, 5); STEP(17, 5); STEP(18, 5); STEP(19, 5);
        STEP(20, 5); STEP(21, 5); STEP(22, 5); STEP(23, 5); STEP(24, 5);
        STEP(25, 4); STEP(26, 3); STEP(27, 2); STEP(28, 1); STEP(29, 0);
#undef STEP
#undef GLD

        uint4 pk;
        pk.x = f2bf(clip01(ac[0])) | (f2bf(clip01(ac[1])) << 16);
        pk.y = f2bf(clip01(ac[2])) | (f2bf(clip01(ac[3])) << 16);
        pk.z = f2bf(clip01(ac[4])) | (f2bf(clip01(ac[5])) << 16);
        pk.w = f2bf(clip01(ac[6])) | (f2bf(clip01(ac[7])) << 16);
        const int colb = (side * 1024 + slice * 128 + li * 16) ^ ((p & 7) << 4);
        *(uint4*)((char*)xg + (size_t)(pblk + p) * 2048 + colb) = pk;
    }
}

// ---------------------------------------------------------------------------
// Kernel 2: MLP. x arrives already in the swizzled LDS layout -> linear 32KB
// stage. MFMA layer1 + layers 2/3 identical to r9/r10 (verified).
// ---------------------------------------------------------------------------
__global__ __launch_bounds__(256, 4) void mlp2(
    const unsigned int* __restrict__ xg,        // [NPOS][512] uints, swizzled
    const unsigned int* __restrict__ w1f,       // frag-ordered bf16
    const float* __restrict__ b1,
    const float* __restrict__ W2, const float* __restrict__ b2,
    const float* __restrict__ W3, const float* __restrict__ b3,
    float* __restrict__ out)
{
    __shared__ __align__(16) char smem[32768];
    char* xb   = smem;
    float* h1  = (float*)smem;                  // [16][132]
    float* w2  = (float*)smem + 16 * 132;       // [32][132]
    float* h2  = (float*)smem + 48 * 132;       // [16][33]

    const int t    = threadIdx.x;               // 0..255
    const int pblk = blockIdx.x * MT;
    const int w    = t >> 6;
    const int lane = t & 63;

    // ---- stage x tile: linear 32KB copy ----
    {
        const uint4* src = (const uint4*)((const char*)xg + (size_t)pblk * 2048);
#pragma unroll
        for (int i = 0; i < 8; ++i) {
            int f = t + i * 256;
            *(uint4*)(xb + f * 16) = src[f];
        }
    }
    __syncthreads();

    // ---- layer1 GEMM via MFMA (M=16, N=128, K=1024) ----
    const int l15 = lane & 15, lg = lane >> 4, lq = lane & 7;
    f32x4 acc0 = {}, acc1 = {};
    const int arow = l15 * 2048;
    const bf16x8* w1v = (const bf16x8*)w1f;
#pragma unroll 4
    for (int ks = 0; ks < 32; ++ks) {
        const int acol = (ks * 64 + lg * 16) ^ (lq << 4);
        bf16x8 a0  = *(const bf16x8*)(xb + arow + acol);
        bf16x8 bf0 = w1v[((2 * w + 0) * 32 + ks) * 64 + lane];
        bf16x8 bf1 = w1v[((2 * w + 1) * 32 + ks) * 64 + lane];
        acc0 = __builtin_amdgcn_mfma_f32_16x16x32_bf16(a0, bf0, acc0, 0, 0, 0);
        acc1 = __builtin_amdgcn_mfma_f32_16x16x32_bf16(a0, bf1, acc1, 0, 0, 0);
    }
    __syncthreads();   // x tile dead; smem becomes h1/w2/h2

    // ---- epilogue: bias + clip -> h1[16][132] ----
    {
        const int o0 = (2 * w + 0) * 16 + l15;
        const int o1 = (2 * w + 1) * 16 + l15;
        const float bb0 = b1[o0], bb1 = b1[o1];
#pragma unroll
        for (int r = 0; r < 4; ++r) {
            int p0 = lg * 4 + r;
            h1[p0 * 132 + o0] = clip01(acc0[r] + bb0);
            h1[p0 * 132 + o1] = clip01(acc1[r] + bb1);
        }
    }
    // stage W2 (32x128)
#pragma unroll
    for (int i = 0; i < 16; ++i) {
        int f = t + i * 256;
        int o = f >> 7, k = f & 127;
        w2[o * 132 + k] = W2[o * 128 + k];
    }
    __syncthreads();

    // ---- layer2: 16 pos x 32 out ----
    {
        const int p2 = t >> 4;
        const int ob = (t & 15) * 2;
        float s0 = b2[ob], s1 = b2[ob + 1];
#pragma unroll
        for (int k4 = 0; k4 < 32; ++k4) {
            float4 h4 = *(const float4*)(h1 + p2 * 132 + k4 * 4);
            float4 wa = *(const float4*)(w2 + ob * 132 + k4 * 4);
            float4 wb = *(const float4*)(w2 + (ob + 1) * 132 + k4 * 4);
            s0 += h4.x * wa.x + h4.y * wa.y + h4.z * wa.z + h4.w * wa.w;
            s1 += h4.x * wb.x + h4.y * wb.y + h4.z * wb.z + h4.w * wb.w;
        }
        h2[p2 * 33 + ob]     = clip01(s0);
        h2[p2 * 33 + ob + 1] = clip01(s1);
    }
    __syncthreads();

    // ---- layer3 + tanh ----
    if (t < MT) {
        float s = b3[0];
#pragma unroll
        for (int k = 0; k < 32; ++k) s += h2[t * 33 + k] * W3[k];
        out[pblk + t] = tanhf(s);
    }
}

// ---------------------------------------------------------------------------
extern "C" void kernel_launch(void* const* d_in, const int* in_sizes, int n_in,
                              void* d_out, int out_size, void* d_ws, size_t ws_size,
                              hipStream_t stream) {
    const int*   stm_idx  = (const int*)  d_in[0];
    const int*   nstm_idx = (const int*)  d_in[2];
    const float* emb      = (const float*)d_in[4];
    const float* W1       = (const float*)d_in[5];
    const float* b1       = (const float*)d_in[6];
    const float* W2       = (const float*)d_in[7];
    const float* b2       = (const float*)d_in[8];
    const float* W3       = (const float*)d_in[9];
    const float* b3       = (const float*)d_in[10];
    float*       out      = (float*)d_out;

    unsigned int* embbf = (unsigned int*)d_ws;                        // 41,943,040 B
    unsigned int* w1f   = (unsigned int*)((char*)d_ws + 41943040);    //    262,144 B
    unsigned int* xg    = (unsigned int*)((char*)d_ws + 42205184);    // 33,554,432 B

    cvt_emb<<<2048, 256, 0, stream>>>(emb, embbf);
    prep_w1<<<64, 256, 0, stream>>>(W1, w1f);
    gather_slices<<<2048, 256, 0, stream>>>(stm_idx, nstm_idx, embbf, xg);
    mlp2<<<NPOS / MT, 256, 0, stream>>>(xg, w1f, b1, W2, b2, W3, b3, out);
}